// Round 14
// baseline (4090.580 us; speedup 1.0000x reference)
//
#include <hip/hip_runtime.h>
#include <hip/hip_bf16.h>
#include <math.h>

typedef __attribute__((ext_vector_type(4))) float f32x4;
typedef __attribute__((ext_vector_type(8))) short bf16x8;
typedef __attribute__((ext_vector_type(4))) float float4v;
typedef unsigned short u16;
typedef unsigned int u32;

#define DIM 768
#define SEQ 2048
#define NTOK 4096
#define NH 12
#define NL 12
#define VOCAB 50257

__device__ __forceinline__ u16 f2bf(float f) {
  union { float f; u32 u; } c; c.f = f;
  u32 u = c.u;
  u32 r = u + 0x7fffu + ((u >> 16) & 1u);
  return (u16)(r >> 16);
}

__device__ __forceinline__ float fexp2(float x) {
#if __has_builtin(__builtin_amdgcn_exp2f)
  return __builtin_amdgcn_exp2f(x);
#else
  return exp2f(x);
#endif
}

__device__ __forceinline__ f32x4 mfma_bf16(bf16x8 a, bf16x8 b, f32x4 c) {
  return __builtin_amdgcn_mfma_f32_16x16x32_bf16(a, b, c, 0, 0, 0);
}

// async global->LDS direct copy, 16 bytes per lane. LDS dest must be linear
// in lane (wave-uniform base + lane*16) — guaranteed by caller's tid mapping.
__device__ __forceinline__ void gload_lds16(const u16* g, u16* l) {
  __builtin_amdgcn_global_load_lds((const __attribute__((address_space(1))) u32*)g,
                                   (__attribute__((address_space(3))) u32*)l, 16, 0, 0);
}

// ---------------- embedding: x[n,d] = wte[idx[n],d] + wpe[n%SEQ,d] ----------------
__global__ void embed_k(const int* __restrict__ idx, const float* __restrict__ wte,
                        const float* __restrict__ wpe, float* __restrict__ x) {
  int t = blockIdx.x * 256 + threadIdx.x;  // NTOK*192 float4 total, grid sized exactly
  int n = t / 192, c = t % 192;
  int tok = idx[n];
  float4v a = ((const float4v*)wte)[(size_t)tok * 192 + c];
  float4v p = ((const float4v*)wpe)[(size_t)(n & (SEQ - 1)) * 192 + c];
  ((float4v*)x)[t] = a + p;
}

// ---------------- layernorm: one wave per row, f32 in -> bf16 out ----------------
__global__ __launch_bounds__(256) void ln_k(const float* __restrict__ x,
                                            const float* __restrict__ w,
                                            const float* __restrict__ b,
                                            u16* __restrict__ out) {
  int lane = threadIdx.x & 63;
  int row = blockIdx.x * 4 + (threadIdx.x >> 6);
  const float4v* xr = (const float4v*)(x + (size_t)row * DIM);
  float4v v[3];
#pragma unroll
  for (int i = 0; i < 3; ++i) v[i] = xr[i * 64 + lane];
  float s = 0.f;
#pragma unroll
  for (int i = 0; i < 3; ++i)
#pragma unroll
    for (int j = 0; j < 4; ++j) s += v[i][j];
#pragma unroll
  for (int o = 1; o < 64; o <<= 1) s += __shfl_xor(s, o);
  float mu = s * (1.f / 768.f);
  float vs = 0.f;
#pragma unroll
  for (int i = 0; i < 3; ++i)
#pragma unroll
    for (int j = 0; j < 4; ++j) { float d = v[i][j] - mu; vs += d * d; }
#pragma unroll
  for (int o = 1; o < 64; o <<= 1) vs += __shfl_xor(vs, o);
  float rs = rsqrtf(vs * (1.f / 768.f) + 1e-5f);
  u16* orow = out + (size_t)row * DIM;
#pragma unroll
  for (int i = 0; i < 3; ++i) {
    float4v wv = ((const float4v*)w)[i * 64 + lane];
    float4v bv = ((const float4v*)b)[i * 64 + lane];
    float y0 = (v[i][0] - mu) * rs * wv[0] + bv[0];
    float y1 = (v[i][1] - mu) * rs * wv[1] + bv[1];
    float y2 = (v[i][2] - mu) * rs * wv[2] + bv[2];
    float y3 = (v[i][3] - mu) * rs * wv[3] + bv[3];
    uint2 pk;
    pk.x = (u32)f2bf(y0) | ((u32)f2bf(y1) << 16);
    pk.y = (u32)f2bf(y2) | ((u32)f2bf(y3) << 16);
    ((uint2*)orow)[i * 64 + lane] = pk;
  }
}

// ---------------- f32 -> bf16 convert (grid-stride over float4s) ----------------
__global__ void cvt_k(const float* __restrict__ src, u16* __restrict__ dst, int n4) {
  int stride = gridDim.x * blockDim.x;
  for (int i = blockIdx.x * blockDim.x + threadIdx.x; i < n4; i += stride) {
    float4v v = ((const float4v*)src)[i];
    uint2 pk;
    pk.x = (u32)f2bf(v[0]) | ((u32)f2bf(v[1]) << 16);
    pk.y = (u32)f2bf(v[2]) | ((u32)f2bf(v[3]) << 16);
    ((uint2*)dst)[i] = pk;
  }
}

// ---------------- GEMM 128² (m97 structure) — used for outproj/fc2 ----------------
// EPI 2: resid += C.
template <int EPI>
__global__ __launch_bounds__(256) void gemm_bt(const u16* __restrict__ A,
                                               const u16* __restrict__ W, int Mdim,
                                               int Kdim, u16* __restrict__ outb,
                                               float* __restrict__ resid) {
  __shared__ u16 lA[128 * 64];
  __shared__ u16 lW[128 * 64];
  const int m0 = blockIdx.y * 128;
  const int n0 = blockIdx.x * 128;
  const int tid = threadIdx.x;
  const int lane = tid & 63, wv = tid >> 6;
  const int wr = wv >> 1, wc = wv & 1;
  const int lr = lane & 15, hi = lane >> 4;

  f32x4 acc[4][4];
#pragma unroll
  for (int i = 0; i < 4; ++i)
#pragma unroll
    for (int j = 0; j < 4; ++j) acc[i][j] = (f32x4){0.f, 0.f, 0.f, 0.f};

  const int s_row = tid >> 3;
  const int s_col = (tid & 7) * 8;
  int wrow[4];
#pragma unroll
  for (int it = 0; it < 4; ++it) {
    int r = m0 + s_row + it * 32;
    wrow[it] = (r < Mdim) ? r : (Mdim - 1);
  }

  for (int k0 = 0; k0 < Kdim; k0 += 64) {
    __syncthreads();
#pragma unroll
    for (int it = 0; it < 4; ++it) {
      gload_lds16(A + (size_t)(n0 + s_row + it * 32) * Kdim + k0 + s_col,
                  &lA[(s_row + it * 32) * 64 + s_col]);
      gload_lds16(W + (size_t)wrow[it] * Kdim + k0 + s_col,
                  &lW[(s_row + it * 32) * 64 + s_col]);
    }
    __syncthreads();
#pragma unroll
    for (int kk = 0; kk < 2; ++kk) {
      bf16x8 af[4], wf[4];
#pragma unroll
      for (int i = 0; i < 4; ++i)
        af[i] = *(const bf16x8*)(&lA[(wr * 64 + i * 16 + lr) * 64 + kk * 32 + hi * 8]);
#pragma unroll
      for (int j = 0; j < 4; ++j)
        wf[j] = *(const bf16x8*)(&lW[(wc * 64 + j * 16 + lr) * 64 + kk * 32 + hi * 8]);
#pragma unroll
      for (int i = 0; i < 4; ++i)
#pragma unroll
        for (int j = 0; j < 4; ++j) acc[i][j] = mfma_bf16(af[i], wf[j], acc[i][j]);
    }
  }

#pragma unroll
  for (int i = 0; i < 4; ++i) {
#pragma unroll
    for (int j = 0; j < 4; ++j) {
      int nb = n0 + wr * 64 + i * 16 + hi * 4;
      int m = m0 + wc * 64 + j * 16 + lr;
#pragma unroll
      for (int r = 0; r < 4; ++r) {
        float val = acc[i][j][r];
        size_t o = (size_t)(nb + r) * Mdim + m;
        if (EPI == 0) {
          if (m < Mdim) outb[o] = f2bf(val);
        } else if (EPI == 1) {
          float g = 0.5f * val * (1.f + erff(val * 0.70710678118f));
          outb[o] = f2bf(g);
        } else if (EPI == 2) {
          resid[o] += val;
        } else {
          if (m < Mdim) resid[o] = val;
        }
      }
    }
  }
}

// ---------------- GEMM 256² deep-pipeline (T3+T4+T5 + T2 swizzle) ----------------
// 8 waves (2M x 4N), 512 thr, BK=64, 128 KiB double-buffered LDS, counted vmcnt.
// T2 per rule #21: gload_lds dest LINEAR; global SOURCE col inverse-swizzled
// (col ^= (row&7)<<3, involution); reads apply the same XOR -> conflict-free.
// EPI 0: bf16 out. EPI 1: exact GELU -> bf16. EPI 3: f32 out (m guard).
template <int EPI>
__global__ __launch_bounds__(512) void gemm256(const u16* __restrict__ A,
                                               const u16* __restrict__ W, int Mdim,
                                               int Kdim, u16* __restrict__ outb,
                                               float* __restrict__ resid) {
  __shared__ u16 lA[2][256 * 64];
  __shared__ u16 lB[2][256 * 64];
  const int n0 = blockIdx.x * 256;  // token rows
  const int m0 = blockIdx.y * 256;  // feature cols
  const int tid = threadIdx.x;
  const int lane = tid & 63, wid = tid >> 6;
  const int wr = wid >> 2, wc = wid & 3;  // 2 x 4 wave grid
  const int lr = lane & 15, hi = lane >> 4;

  const int s_row = tid >> 3;        // 0..63 (LDS row & 7 == s_row & 7 for all it)
  const int s_col = (tid & 7) * 8;   // LDS dest byte = tid*16 (+ it*8192): lane-linear
  const int g_col = s_col ^ ((s_row & 7) << 3);  // inverse-swizzled global col
  int wrow[4];
#pragma unroll
  for (int it = 0; it < 4; ++it) {
    int r = m0 + s_row + it * 64;
    wrow[it] = (r < Mdim) ? r : (Mdim - 1);  // clamp at M edge; epilogue guards
  }

  f32x4 acc[8][4];
#pragma unroll
  for (int i = 0; i < 8; ++i)
#pragma unroll
    for (int j = 0; j < 4; ++j) acc[i][j] = (f32x4){0.f, 0.f, 0.f, 0.f};

  const int nt = Kdim >> 6;

  auto stage = [&](int kt, int buf) {
    const int k0 = kt * 64;
#pragma unroll
    for (int it = 0; it < 4; ++it)
      gload_lds16(A + (size_t)(n0 + s_row + it * 64) * Kdim + k0 + g_col,
                  &lA[buf][(s_row + it * 64) * 64 + s_col]);
#pragma unroll
    for (int it = 0; it < 4; ++it)
      gload_lds16(W + (size_t)wrow[it] * Kdim + k0 + g_col,
                  &lB[buf][(s_row + it * 64) * 64 + s_col]);
  };

  // fragment-read swizzle: row&7 == lr&7 for all fragment rows (multiples of 8/16)
  const int swz = (lr & 7) << 3;

  // prologue: two tiles in flight; wait only for tile 0 (tile 1's 8 stay pending)
  stage(0, 0);
  stage(1, 1);
  asm volatile("s_waitcnt vmcnt(8)" ::: "memory");
  __builtin_amdgcn_s_barrier();

  for (int t = 0; t < nt; ++t) {
    const int cur = t & 1;
    const u16* la = lA[cur];
    const u16* lb = lB[cur];
#pragma unroll
    for (int kk = 0; kk < 2; ++kk) {
      const int csw = (kk * 32 + hi * 8) ^ swz;
      bf16x8 af[8], wf[4];
#pragma unroll
      for (int i = 0; i < 8; ++i)
        af[i] = *(const bf16x8*)(&la[(wr * 128 + i * 16 + lr) * 64 + csw]);
#pragma unroll
      for (int j = 0; j < 4; ++j)
        wf[j] = *(const bf16x8*)(&lb[(wc * 64 + j * 16 + lr) * 64 + csw]);
      __builtin_amdgcn_s_setprio(1);
#pragma unroll
      for (int i = 0; i < 8; ++i)
#pragma unroll
        for (int j = 0; j < 4; ++j) acc[i][j] = mfma_bf16(af[i], wf[j], acc[i][j]);
      __builtin_amdgcn_s_setprio(0);
    }
    __builtin_amdgcn_s_barrier();  // all waves done READING buf[cur]
    if (t + 2 < nt) {
      stage(t + 2, cur);           // refill just-freed buffer
      asm volatile("s_waitcnt vmcnt(8)" ::: "memory");  // tile t+1 landed; t+2 in flight
    } else if (t + 1 < nt) {
      asm volatile("s_waitcnt vmcnt(0)" ::: "memory");  // epilogue drain
    }
    __builtin_amdgcn_s_barrier();  // everyone's tile t+1 visible
  }

#pragma unroll
  for (int i = 0; i < 8; ++i) {
#pragma unroll
    for (int j = 0; j < 4; ++j) {
      int nb = n0 + wr * 128 + i * 16 + hi * 4;
      int m = m0 + wc * 64 + j * 16 + lr;
#pragma unroll
      for (int r = 0; r < 4; ++r) {
        float val = acc[i][j][r];
        size_t o = (size_t)(nb + r) * Mdim + m;
        if (EPI == 0) {
          if (m < Mdim) outb[o] = f2bf(val);
        } else if (EPI == 1) {
          float g = 0.5f * val * (1.f + erff(val * 0.70710678118f));
          outb[o] = f2bf(g);
        } else {
          if (m < Mdim) resid[o] = val;  // f32 logits out
        }
      }
    }
  }
}

// ---------------- V transpose: qkv V slice -> vT[bh][d][s] ----------------
__global__ __launch_bounds__(256) void vtrans_k(const u16* __restrict__ qkv,
                                                u16* __restrict__ vT) {
  __shared__ u16 t[64][65];
  int bh = blockIdx.y;
  int b = bh / NH, h = bh % NH;
  int s0 = blockIdx.x * 64;
  int tid = threadIdx.x;
  int col = tid & 63, row0 = tid >> 6;
#pragma unroll
  for (int it = 0; it < 16; ++it) {
    int srow = row0 + it * 4;
    t[srow][col] = qkv[(size_t)(b * SEQ + s0 + srow) * 2304 + 1536 + h * 64 + col];
  }
  __syncthreads();
#pragma unroll
  for (int it = 0; it < 16; ++it) {
    int drow = row0 + it * 4;
    vT[((size_t)bh * 64 + drow) * SEQ + s0 + col] = t[col][drow];
  }
}

// ---------------- flash attention: 8 waves/block, 128-kv tiles, zig-zag pair ----
// Per 128-kv tile: ONE barrier pair (vs two at 64-kv) staging lK[128][80] (K rows)
// and lV[64][136] (V^T, kv 0..127). Softmax is 64-kv-wide: one shuffle-max chain
// and one (conditional, T13) rescale per 64 kv. P per wave [16][76]. Same verified
// fragment layouts / masking / P write-rows(hi*4+r)+read-rows(lr) redistribution.
// Causal bound qb+128 is a multiple of 128 -> even tiling; barriers block-uniform
// (the per-wave skip contains no barriers).
__global__ __launch_bounds__(512) void flash_k(const u16* __restrict__ qkv,
                                               const u16* __restrict__ vT,
                                               u16* __restrict__ ctx) {
  const int tid = threadIdx.x;
  const int lane = tid & 63, wq = tid >> 6;
  const int lr = lane & 15, hi = lane >> 4;
  const int pi = blockIdx.x;  // 0..7
  const int bh = blockIdx.y;
  const int b = bh / NH, h = bh % NH;
  const size_t rowb = (size_t)b * SEQ;
  const float SCL = 0.125f * 1.44269504f;  // 1/sqrt(64) * log2(e)

  __shared__ u16 lK[128 * 80];     // [kv 0..127][d], stride 80
  __shared__ u16 lV[64 * 136];     // [d][kv 0..127], stride 136
  __shared__ u16 Pb[8][16 * 76];   // per-wave P [16 q][64 kv], stride 76
  u16* P = Pb[wq];

  const int s_row = tid >> 3;          // 0..63
  const int s_col = (tid & 7) * 8;     // 0,8,..,56
  const u16* kSrc = qkv + rowb * 2304 + 768 + h * 64;       // +(k+row)*2304+col
  const u16* vSrc = vT + ((size_t)bh * 64 + s_row) * SEQ;   // +k+col

#pragma unroll
  for (int pass = 0; pass < 2; ++pass) {
    const int qb = (pass == 0 ? (15 - pi) : pi) * 128;
    const int qa = qb + wq * 16;  // this wave's 16 q-rows

    const u16* Qp = qkv + (rowb + qa + lr) * 2304 + h * 64 + hi * 8;
    bf16x8 qf0 = *(const bf16x8*)(Qp);
    bf16x8 qf1 = *(const bf16x8*)(Qp + 32);

    f32x4 o[4];
    float mreg[4], lreg[4];
#pragma unroll
    for (int ct = 0; ct < 4; ++ct) o[ct] = (f32x4){0.f, 0.f, 0.f, 0.f};
#pragma unroll
    for (int r = 0; r < 4; ++r) { mreg[r] = -1e30f; lreg[r] = 0.f; }

    const int kEnd = qb + 128;  // exclusive causal bound; multiple of 128
    bf16x8 kr0 = *(const bf16x8*)(kSrc + (size_t)s_row * 2304 + s_col);
    bf16x8 kr1 = *(const bf16x8*)(kSrc + (size_t)(s_row + 64) * 2304 + s_col);
    bf16x8 vr0 = *(const bf16x8*)(vSrc + s_col);
    bf16x8 vr1 = *(const bf16x8*)(vSrc + 64 + s_col);

    for (int k0 = 0; k0 < kEnd; k0 += 128) {
      __syncthreads();  // all waves done reading previous tile (covers cross-pass too)
      *(bf16x8*)(&lK[s_row * 80 + s_col]) = kr0;
      *(bf16x8*)(&lK[(s_row + 64) * 80 + s_col]) = kr1;
      *(bf16x8*)(&lV[s_row * 136 + s_col]) = vr0;
      *(bf16x8*)(&lV[s_row * 136 + 64 + s_col]) = vr1;
      __syncthreads();  // tile visible
      if (k0 + 128 < kEnd) {  // prefetch next tile under compute
        kr0 = *(const bf16x8*)(kSrc + (size_t)(k0 + 128 + s_row) * 2304 + s_col);
        kr1 = *(const bf16x8*)(kSrc + (size_t)(k0 + 192 + s_row) * 2304 + s_col);
        vr0 = *(const bf16x8*)(vSrc + k0 + 128 + s_col);
        vr1 = *(const bf16x8*)(vSrc + k0 + 192 + s_col);
      }
#pragma unroll
      for (int sub = 0; sub < 2; ++sub) {
        const int kg = k0 + sub * 64;
        if (kg > qa + 15) continue;  // wave-uniform causal skip (no barriers inside)
        f32x4 s[4];
#pragma unroll
        for (int j = 0; j < 4; ++j) s[j] = (f32x4){0.f, 0.f, 0.f, 0.f};
#pragma unroll
        for (int j = 0; j < 4; ++j) {
          const u16* kp = &lK[(sub * 64 + j * 16 + lr) * 80 + hi * 8];
          bf16x8 ka = *(const bf16x8*)(kp);
          bf16x8 kc = *(const bf16x8*)(kp + 32);
          s[j] = mfma_bf16(qf0, ka, s[j]);
          s[j] = mfma_bf16(qf1, kc, s[j]);
        }
        float mnew[4];
        int grew = 0;
#pragma unroll
        for (int r = 0; r < 4; ++r) {
          int qrow = qa + hi * 4 + r;
#pragma unroll
          for (int j = 0; j < 4; ++j) {
            float v = s[j][r] * SCL;
            if (kg + j * 16 + lr > qrow) v = -1e30f;
            s[j][r] = v;
          }
          float m01 = fmaxf(fmaxf(s[0][r], s[1][r]), fmaxf(s[2][r], s[3][r]));
          m01 = fmaxf(m01, __shfl_xor(m01, 1));
          m01 = fmaxf(m01, __shfl_xor(m01, 2));
          m01 = fmaxf(m01, __shfl_xor(m01, 4));
          m01 = fmaxf(m01, __shfl_xor(m01, 8));
          mnew[r] = fmaxf(mreg[r], m01);
          grew |= (mnew[r] > mreg[r]) ? 1 : 0;
        }
        if (__any(grew)) {  // T13: skip exact-1 rescale (cor==1 for all rows)
#pragma unroll
          for (int r = 0; r < 4; ++r) {
            float c = fexp2(mreg[r] - mnew[r]);
            lreg[r] *= c;
#pragma unroll
            for (int ct = 0; ct < 4; ++ct) o[ct][r] *= c;
            mreg[r] = mnew[r];
          }
        }
#pragma unroll
        for (int r = 0; r < 4; ++r) {
          float p0 = fexp2(s[0][r] - mreg[r]);
          float p1 = fexp2(s[1][r] - mreg[r]);
          float p2 = fexp2(s[2][r] - mreg[r]);
          float p3 = fexp2(s[3][r] - mreg[r]);
          lreg[r] += p0 + p1 + p2 + p3;
          u16* pr = &P[(hi * 4 + r) * 76];
          pr[lr] = f2bf(p0);
          pr[16 + lr] = f2bf(p1);
          pr[32 + lr] = f2bf(p2);
          pr[48 + lr] = f2bf(p3);
        }
        bf16x8 pa0 = *(const bf16x8*)(&P[lr * 76 + hi * 8]);
        bf16x8 pa1 = *(const bf16x8*)(&P[lr * 76 + 32 + hi * 8]);
#pragma unroll
        for (int ct = 0; ct < 4; ++ct) {
          const u16* vp = &lV[(ct * 16 + lr) * 136 + sub * 64];
          bf16x8 vf0 = *(const bf16x8*)(vp + hi * 8);
          bf16x8 vf1 = *(const bf16x8*)(vp + 32 + hi * 8);
          o[ct] = mfma_bf16(pa0, vf0, o[ct]);
          o[ct] = mfma_bf16(pa1, vf1, o[ct]);
        }
      }
    }

    float lfin[4];
#pragma unroll
    for (int r = 0; r < 4; ++r) {
      float l = lreg[r];
      l += __shfl_xor(l, 1);
      l += __shfl_xor(l, 2);
      l += __shfl_xor(l, 4);
      l += __shfl_xor(l, 8);
      lfin[r] = 1.f / l;
    }
#pragma unroll
    for (int ct = 0; ct < 4; ++ct)
#pragma unroll
      for (int r = 0; r < 4; ++r) {
        float ov = o[ct][r] * lfin[r];
        size_t n = rowb + qa + hi * 4 + r;
        ctx[n * DIM + h * 64 + ct * 16 + lr] = f2bf(ov);
      }
  }
}

extern "C" void kernel_launch(void* const* d_in, const int* in_sizes, int n_in,
                              void* d_out, int out_size, void* d_ws, size_t ws_size,
                              hipStream_t stream) {
  (void)in_sizes; (void)n_in; (void)out_size; (void)ws_size;
  const int* idx = (const int*)d_in[0];
  const float* wte = (const float*)d_in[1];
  const float* wpe = (const float*)d_in[2];
  const float* ln1w = (const float*)d_in[3];
  const float* ln1b = (const float*)d_in[4];
  const float* qkvw = (const float*)d_in[5];
  const float* outw = (const float*)d_in[6];
  const float* ln2w = (const float*)d_in[7];
  const float* ln2b = (const float*)d_in[8];
  const float* fc1w = (const float*)d_in[9];
  const float* fc2w = (const float*)d_in[10];
  const float* lnfw = (const float*)d_in[11];
  const float* lnfb = (const float*)d_in[12];
  float* out = (float*)d_out;  // reference output dtype is float32

  // ws holds only buffers live during the final logits GEMM (proven footprint).
  char* ws = (char*)d_ws;
  size_t off = 0;
  auto carve = [&](size_t bytes) {
    char* p = ws + off;
    off += (bytes + 255) & ~(size_t)255;
    return p;
  };
  u16* hb = (u16*)carve((size_t)NTOK * DIM * 2);   // post-LN bf16 (live at final GEMM)
  u16* wteb = (u16*)carve((size_t)VOCAB * DIM * 2);  // wte bf16 (live at final GEMM)

  // Everything dead before the final GEMM lives in d_out (824 MB), which the
  // final GEMM fully overwrites. Deterministic: rebuilt every call.
  char* os = (char*)d_out;
  size_t ooff = 0;
  auto ocarve = [&](size_t bytes) {
    char* p = os + ooff;
    ooff += (bytes + 255) & ~(size_t)255;
    return p;
  };
  float* xb = (float*)ocarve((size_t)NTOK * DIM * 4);      // residual stream f32
  u16* qkvb = (u16*)ocarve((size_t)NTOK * 3 * DIM * 2);    // qkv bf16
  u16* ctxb = (u16*)ocarve((size_t)NTOK * DIM * 2);        // attn output bf16
  u16* mhb = (u16*)ocarve((size_t)NTOK * 4 * DIM * 2);     // mlp hidden bf16
  u16* vTb = (u16*)ocarve((size_t)2 * NH * 64 * SEQ * 2);  // V transposed
  u16* qkvwb = (u16*)ocarve((size_t)NL * 1769472 * 2);     // all-layer bf16 weights
  u16* outwb = (u16*)ocarve((size_t)NL * 589824 * 2);
  u16* fc1wb = (u16*)ocarve((size_t)NL * 2359296 * 2);
  u16* fc2wb = (u16*)ocarve((size_t)NL * 2359296 * 2);     // total ~245 MB < 824 MB

  // one-time (per call) weight conversion: 5 launches
  cvt_k<<<2048, 256, 0, stream>>>(qkvw, qkvwb, NL * 442368);
  cvt_k<<<2048, 256, 0, stream>>>(outw, outwb, NL * 147456);
  cvt_k<<<2048, 256, 0, stream>>>(fc1w, fc1wb, NL * 589824);
  cvt_k<<<2048, 256, 0, stream>>>(fc2w, fc2wb, NL * 589824);
  cvt_k<<<2048, 256, 0, stream>>>(wte, wteb, 9649344);

  embed_k<<<3072, 256, 0, stream>>>(idx, wte, wpe, xb);

  for (int l = 0; l < NL; ++l) {
    ln_k<<<1024, 256, 0, stream>>>(xb, ln1w + l * DIM, ln1b + l * DIM, hb);
    gemm256<0><<<dim3(16, 9), 512, 0, stream>>>(hb, qkvwb + (size_t)l * 1769472,
                                                2304, 768, qkvb, nullptr);
    vtrans_k<<<dim3(32, 24), 256, 0, stream>>>(qkvb, vTb);
    flash_k<<<dim3(8, 24), 512, 0, stream>>>(qkvb, vTb, ctxb);
    gemm_bt<2><<<dim3(32, 6), 256, 0, stream>>>(ctxb, outwb + (size_t)l * 589824,
                                                768, 768, nullptr, xb);
    ln_k<<<1024, 256, 0, stream>>>(xb, ln2w + l * DIM, ln2b + l * DIM, hb);
    gemm256<1><<<dim3(16, 12), 512, 0, stream>>>(hb, fc1wb + (size_t)l * 2359296,
                                                 3072, 768, mhb, nullptr);
    gemm_bt<2><<<dim3(32, 6), 256, 0, stream>>>(mhb, fc2wb + (size_t)l * 2359296,
                                                768, 3072, nullptr, xb);
  }

  ln_k<<<1024, 256, 0, stream>>>(xb, lnfw, lnfb, hb);
  gemm256<3><<<dim3(16, 197), 512, 0, stream>>>(hb, wteb, VOCAB, 768, nullptr, out);
}

// Round 15
// 3977.942 us; speedup vs baseline: 1.0283x; 1.0283x over previous
//
#include <hip/hip_runtime.h>
#include <hip/hip_bf16.h>
#include <math.h>

typedef __attribute__((ext_vector_type(4))) float f32x4;
typedef __attribute__((ext_vector_type(8))) short bf16x8;
typedef __attribute__((ext_vector_type(4))) float float4v;
typedef unsigned short u16;
typedef unsigned int u32;

#define DIM 768
#define SEQ 2048
#define NTOK 4096
#define NH 12
#define NL 12
#define VOCAB 50257

__device__ __forceinline__ u16 f2bf(float f) {
  union { float f; u32 u; } c; c.f = f;
  u32 u = c.u;
  u32 r = u + 0x7fffu + ((u >> 16) & 1u);
  return (u16)(r >> 16);
}

__device__ __forceinline__ float fexp2(float x) {
#if __has_builtin(__builtin_amdgcn_exp2f)
  return __builtin_amdgcn_exp2f(x);
#else
  return exp2f(x);
#endif
}

__device__ __forceinline__ f32x4 mfma_bf16(bf16x8 a, bf16x8 b, f32x4 c) {
  return __builtin_amdgcn_mfma_f32_16x16x32_bf16(a, b, c, 0, 0, 0);
}

// async global->LDS direct copy, 16 bytes per lane. LDS dest must be linear
// in lane (wave-uniform base + lane*16) — guaranteed by caller's tid mapping.
__device__ __forceinline__ void gload_lds16(const u16* g, u16* l) {
  __builtin_amdgcn_global_load_lds((const __attribute__((address_space(1))) u32*)g,
                                   (__attribute__((address_space(3))) u32*)l, 16, 0, 0);
}

// ---------------- embedding: x[n,d] = wte[idx[n],d] + wpe[n%SEQ,d] ----------------
__global__ void embed_k(const int* __restrict__ idx, const float* __restrict__ wte,
                        const float* __restrict__ wpe, float* __restrict__ x) {
  int t = blockIdx.x * 256 + threadIdx.x;  // NTOK*192 float4 total, grid sized exactly
  int n = t / 192, c = t % 192;
  int tok = idx[n];
  float4v a = ((const float4v*)wte)[(size_t)tok * 192 + c];
  float4v p = ((const float4v*)wpe)[(size_t)(n & (SEQ - 1)) * 192 + c];
  ((float4v*)x)[t] = a + p;
}

// ---------------- layernorm: one wave per row, f32 in -> bf16 out ----------------
__global__ __launch_bounds__(256) void ln_k(const float* __restrict__ x,
                                            const float* __restrict__ w,
                                            const float* __restrict__ b,
                                            u16* __restrict__ out) {
  int lane = threadIdx.x & 63;
  int row = blockIdx.x * 4 + (threadIdx.x >> 6);
  const float4v* xr = (const float4v*)(x + (size_t)row * DIM);
  float4v v[3];
#pragma unroll
  for (int i = 0; i < 3; ++i) v[i] = xr[i * 64 + lane];
  float s = 0.f;
#pragma unroll
  for (int i = 0; i < 3; ++i)
#pragma unroll
    for (int j = 0; j < 4; ++j) s += v[i][j];
#pragma unroll
  for (int o = 1; o < 64; o <<= 1) s += __shfl_xor(s, o);
  float mu = s * (1.f / 768.f);
  float vs = 0.f;
#pragma unroll
  for (int i = 0; i < 3; ++i)
#pragma unroll
    for (int j = 0; j < 4; ++j) { float d = v[i][j] - mu; vs += d * d; }
#pragma unroll
  for (int o = 1; o < 64; o <<= 1) vs += __shfl_xor(vs, o);
  float rs = rsqrtf(vs * (1.f / 768.f) + 1e-5f);
  u16* orow = out + (size_t)row * DIM;
#pragma unroll
  for (int i = 0; i < 3; ++i) {
    float4v wv = ((const float4v*)w)[i * 64 + lane];
    float4v bv = ((const float4v*)b)[i * 64 + lane];
    float y0 = (v[i][0] - mu) * rs * wv[0] + bv[0];
    float y1 = (v[i][1] - mu) * rs * wv[1] + bv[1];
    float y2 = (v[i][2] - mu) * rs * wv[2] + bv[2];
    float y3 = (v[i][3] - mu) * rs * wv[3] + bv[3];
    uint2 pk;
    pk.x = (u32)f2bf(y0) | ((u32)f2bf(y1) << 16);
    pk.y = (u32)f2bf(y2) | ((u32)f2bf(y3) << 16);
    ((uint2*)orow)[i * 64 + lane] = pk;
  }
}

// ---------------- f32 -> bf16 convert (grid-stride over float4s) ----------------
__global__ void cvt_k(const float* __restrict__ src, u16* __restrict__ dst, int n4) {
  int stride = gridDim.x * blockDim.x;
  for (int i = blockIdx.x * blockDim.x + threadIdx.x; i < n4; i += stride) {
    float4v v = ((const float4v*)src)[i];
    uint2 pk;
    pk.x = (u32)f2bf(v[0]) | ((u32)f2bf(v[1]) << 16);
    pk.y = (u32)f2bf(v[2]) | ((u32)f2bf(v[3]) << 16);
    ((uint2*)dst)[i] = pk;
  }
}

// ---------------- GEMM 128² deep-pipeline (gemm256 schedule at 128² tile) --------
// 4 waves (2x2), 256 thr, BK=64, 64 KiB double-buffered LDS, counted vmcnt(8),
// T2 both-sides swizzle (rule #21), setprio around MFMA. Used for outproj/fc2.
// EPI 2: resid += C.
template <int EPI>
__global__ __launch_bounds__(256) void gemm128p(const u16* __restrict__ A,
                                                const u16* __restrict__ W, int Mdim,
                                                int Kdim, u16* __restrict__ outb,
                                                float* __restrict__ resid) {
  __shared__ u16 lA[2][128 * 64];
  __shared__ u16 lW[2][128 * 64];
  const int m0 = blockIdx.y * 128;
  const int n0 = blockIdx.x * 128;
  const int tid = threadIdx.x;
  const int lane = tid & 63, wv = tid >> 6;
  const int wr = wv >> 1, wc = wv & 1;
  const int lr = lane & 15, hi = lane >> 4;

  f32x4 acc[4][4];
#pragma unroll
  for (int i = 0; i < 4; ++i)
#pragma unroll
    for (int j = 0; j < 4; ++j) acc[i][j] = (f32x4){0.f, 0.f, 0.f, 0.f};

  const int s_row = tid >> 3;        // 0..31; LDS rows s_row + it*32 (row&7 == s_row&7)
  const int s_col = (tid & 7) * 8;   // dest byte = tid*16 (+ it*4096): lane-linear
  const int g_col = s_col ^ ((s_row & 7) << 3);  // inverse-swizzled global col
  int wrow[4];
#pragma unroll
  for (int it = 0; it < 4; ++it) {
    int r = m0 + s_row + it * 32;
    wrow[it] = (r < Mdim) ? r : (Mdim - 1);
  }

  const int nt = Kdim >> 6;

  auto stage = [&](int kt, int buf) {
    const int k0 = kt * 64;
#pragma unroll
    for (int it = 0; it < 4; ++it) {
      gload_lds16(A + (size_t)(n0 + s_row + it * 32) * Kdim + k0 + g_col,
                  &lA[buf][(s_row + it * 32) * 64 + s_col]);
      gload_lds16(W + (size_t)wrow[it] * Kdim + k0 + g_col,
                  &lW[buf][(s_row + it * 32) * 64 + s_col]);
    }
  };

  const int swz = (lr & 7) << 3;  // fragment rows are wr*64+i*16+lr -> row&7 == lr&7

  // prologue: two tiles in flight (8 loads each); wait for tile 0 only
  stage(0, 0);
  stage(1, 1);
  asm volatile("s_waitcnt vmcnt(8)" ::: "memory");
  __builtin_amdgcn_s_barrier();

  for (int t = 0; t < nt; ++t) {
    const int cur = t & 1;
    const u16* la = lA[cur];
    const u16* lw = lW[cur];
#pragma unroll
    for (int kk = 0; kk < 2; ++kk) {
      const int csw = (kk * 32 + hi * 8) ^ swz;
      bf16x8 af[4], wf[4];
#pragma unroll
      for (int i = 0; i < 4; ++i)
        af[i] = *(const bf16x8*)(&la[(wr * 64 + i * 16 + lr) * 64 + csw]);
#pragma unroll
      for (int j = 0; j < 4; ++j)
        wf[j] = *(const bf16x8*)(&lw[(wc * 64 + j * 16 + lr) * 64 + csw]);
      __builtin_amdgcn_s_setprio(1);
#pragma unroll
      for (int i = 0; i < 4; ++i)
#pragma unroll
        for (int j = 0; j < 4; ++j) acc[i][j] = mfma_bf16(af[i], wf[j], acc[i][j]);
      __builtin_amdgcn_s_setprio(0);
    }
    __builtin_amdgcn_s_barrier();  // all waves done READING buf[cur]
    if (t + 2 < nt) {
      stage(t + 2, cur);           // refill just-freed buffer
      asm volatile("s_waitcnt vmcnt(8)" ::: "memory");  // t+1 landed; t+2 in flight
    } else if (t + 1 < nt) {
      asm volatile("s_waitcnt vmcnt(0)" ::: "memory");  // epilogue drain
    }
    __builtin_amdgcn_s_barrier();  // everyone's tile t+1 visible
  }

#pragma unroll
  for (int i = 0; i < 4; ++i) {
#pragma unroll
    for (int j = 0; j < 4; ++j) {
      int nb = n0 + wr * 64 + i * 16 + hi * 4;
      int m = m0 + wc * 64 + j * 16 + lr;
#pragma unroll
      for (int r = 0; r < 4; ++r) {
        float val = acc[i][j][r];
        size_t o = (size_t)(nb + r) * Mdim + m;
        if (EPI == 0) {
          if (m < Mdim) outb[o] = f2bf(val);
        } else if (EPI == 1) {
          float g = 0.5f * val * (1.f + erff(val * 0.70710678118f));
          outb[o] = f2bf(g);
        } else if (EPI == 2) {
          resid[o] += val;
        } else {
          if (m < Mdim) resid[o] = val;
        }
      }
    }
  }
}

// ---------------- GEMM 256² deep-pipeline (T3+T4+T5 + T2 swizzle) ----------------
// 8 waves (2M x 4N), 512 thr, BK=64, 128 KiB double-buffered LDS, counted vmcnt.
// T2 per rule #21: gload_lds dest LINEAR; global SOURCE col inverse-swizzled
// (col ^= (row&7)<<3, involution); reads apply the same XOR -> conflict-free.
// EPI 0: bf16 out. EPI 1: exact GELU -> bf16. EPI 3: f32 out (m guard).
template <int EPI>
__global__ __launch_bounds__(512) void gemm256(const u16* __restrict__ A,
                                               const u16* __restrict__ W, int Mdim,
                                               int Kdim, u16* __restrict__ outb,
                                               float* __restrict__ resid) {
  __shared__ u16 lA[2][256 * 64];
  __shared__ u16 lB[2][256 * 64];
  const int n0 = blockIdx.x * 256;  // token rows
  const int m0 = blockIdx.y * 256;  // feature cols
  const int tid = threadIdx.x;
  const int lane = tid & 63, wid = tid >> 6;
  const int wr = wid >> 2, wc = wid & 3;  // 2 x 4 wave grid
  const int lr = lane & 15, hi = lane >> 4;

  const int s_row = tid >> 3;        // 0..63 (LDS row & 7 == s_row & 7 for all it)
  const int s_col = (tid & 7) * 8;   // LDS dest byte = tid*16 (+ it*8192): lane-linear
  const int g_col = s_col ^ ((s_row & 7) << 3);  // inverse-swizzled global col
  int wrow[4];
#pragma unroll
  for (int it = 0; it < 4; ++it) {
    int r = m0 + s_row + it * 64;
    wrow[it] = (r < Mdim) ? r : (Mdim - 1);  // clamp at M edge; epilogue guards
  }

  f32x4 acc[8][4];
#pragma unroll
  for (int i = 0; i < 8; ++i)
#pragma unroll
    for (int j = 0; j < 4; ++j) acc[i][j] = (f32x4){0.f, 0.f, 0.f, 0.f};

  const int nt = Kdim >> 6;

  auto stage = [&](int kt, int buf) {
    const int k0 = kt * 64;
#pragma unroll
    for (int it = 0; it < 4; ++it)
      gload_lds16(A + (size_t)(n0 + s_row + it * 64) * Kdim + k0 + g_col,
                  &lA[buf][(s_row + it * 64) * 64 + s_col]);
#pragma unroll
    for (int it = 0; it < 4; ++it)
      gload_lds16(W + (size_t)wrow[it] * Kdim + k0 + g_col,
                  &lB[buf][(s_row + it * 64) * 64 + s_col]);
  };

  // fragment-read swizzle: row&7 == lr&7 for all fragment rows (multiples of 8/16)
  const int swz = (lr & 7) << 3;

  // prologue: two tiles in flight; wait only for tile 0 (tile 1's 8 stay pending)
  stage(0, 0);
  stage(1, 1);
  asm volatile("s_waitcnt vmcnt(8)" ::: "memory");
  __builtin_amdgcn_s_barrier();

  for (int t = 0; t < nt; ++t) {
    const int cur = t & 1;
    const u16* la = lA[cur];
    const u16* lb = lB[cur];
#pragma unroll
    for (int kk = 0; kk < 2; ++kk) {
      const int csw = (kk * 32 + hi * 8) ^ swz;
      bf16x8 af[8], wf[4];
#pragma unroll
      for (int i = 0; i < 8; ++i)
        af[i] = *(const bf16x8*)(&la[(wr * 128 + i * 16 + lr) * 64 + csw]);
#pragma unroll
      for (int j = 0; j < 4; ++j)
        wf[j] = *(const bf16x8*)(&lb[(wc * 64 + j * 16 + lr) * 64 + csw]);
      __builtin_amdgcn_s_setprio(1);
#pragma unroll
      for (int i = 0; i < 8; ++i)
#pragma unroll
        for (int j = 0; j < 4; ++j) acc[i][j] = mfma_bf16(af[i], wf[j], acc[i][j]);
      __builtin_amdgcn_s_setprio(0);
    }
    __builtin_amdgcn_s_barrier();  // all waves done READING buf[cur]
    if (t + 2 < nt) {
      stage(t + 2, cur);           // refill just-freed buffer
      asm volatile("s_waitcnt vmcnt(8)" ::: "memory");  // tile t+1 landed; t+2 in flight
    } else if (t + 1 < nt) {
      asm volatile("s_waitcnt vmcnt(0)" ::: "memory");  // epilogue drain
    }
    __builtin_amdgcn_s_barrier();  // everyone's tile t+1 visible
  }

#pragma unroll
  for (int i = 0; i < 8; ++i) {
#pragma unroll
    for (int j = 0; j < 4; ++j) {
      int nb = n0 + wr * 128 + i * 16 + hi * 4;
      int m = m0 + wc * 64 + j * 16 + lr;
#pragma unroll
      for (int r = 0; r < 4; ++r) {
        float val = acc[i][j][r];
        size_t o = (size_t)(nb + r) * Mdim + m;
        if (EPI == 0) {
          if (m < Mdim) outb[o] = f2bf(val);
        } else if (EPI == 1) {
          float g = 0.5f * val * (1.f + erff(val * 0.70710678118f));
          outb[o] = f2bf(g);
        } else {
          if (m < Mdim) resid[o] = val;  // f32 logits out
        }
      }
    }
  }
}

// ---------------- V transpose: qkv V slice -> vT[bh][d][s] ----------------
__global__ __launch_bounds__(256) void vtrans_k(const u16* __restrict__ qkv,
                                                u16* __restrict__ vT) {
  __shared__ u16 t[64][65];
  int bh = blockIdx.y;
  int b = bh / NH, h = bh % NH;
  int s0 = blockIdx.x * 64;
  int tid = threadIdx.x;
  int col = tid & 63, row0 = tid >> 6;
#pragma unroll
  for (int it = 0; it < 16; ++it) {
    int srow = row0 + it * 4;
    t[srow][col] = qkv[(size_t)(b * SEQ + s0 + srow) * 2304 + 1536 + h * 64 + col];
  }
  __syncthreads();
#pragma unroll
  for (int it = 0; it < 16; ++it) {
    int drow = row0 + it * 4;
    vT[((size_t)bh * 64 + drow) * SEQ + s0 + col] = t[col][drow];
  }
}

// ---------------- flash attention: 8 waves/block, LDS-shared K/V, zig-zag pair ----
// (round-13 proven version: 64-kv tiles, exp2 softmax, per-lane deferred l-sum)
__global__ __launch_bounds__(512) void flash_k(const u16* __restrict__ qkv,
                                               const u16* __restrict__ vT,
                                               u16* __restrict__ ctx) {
  const int tid = threadIdx.x;
  const int lane = tid & 63, wq = tid >> 6;
  const int lr = lane & 15, hi = lane >> 4;
  const int pi = blockIdx.x;  // 0..7
  const int bh = blockIdx.y;
  const int b = bh / NH, h = bh % NH;
  const size_t rowb = (size_t)b * SEQ;
  const float SCL = 0.125f * 1.44269504f;  // 1/sqrt(64) * log2(e)

  __shared__ u16 lK[64 * 80];      // [kv][d], stride 80
  __shared__ u16 lV[64 * 80];      // [d][kv], stride 80
  __shared__ u16 Pb[8][16 * 40];   // per-wave P, stride 40
  u16* P = Pb[wq];

  const int s_row = tid >> 3;          // 0..63
  const int s_col = (tid & 7) * 8;     // 0,8,..,56
  const u16* kSrc = qkv + rowb * 2304 + 768 + h * 64;       // +(k+row)*2304+col
  const u16* vSrc = vT + ((size_t)bh * 64 + s_row) * SEQ;   // +k+col

#pragma unroll
  for (int pass = 0; pass < 2; ++pass) {
    const int qb = (pass == 0 ? (15 - pi) : pi) * 128;
    const int qa = qb + wq * 16;  // this wave's 16 q-rows

    const u16* Qp = qkv + (rowb + qa + lr) * 2304 + h * 64 + hi * 8;
    bf16x8 qf0 = *(const bf16x8*)(Qp);
    bf16x8 qf1 = *(const bf16x8*)(Qp + 32);

    f32x4 o[4];
    float mreg[4], lreg[4];
#pragma unroll
    for (int ct = 0; ct < 4; ++ct) o[ct] = (f32x4){0.f, 0.f, 0.f, 0.f};
#pragma unroll
    for (int r = 0; r < 4; ++r) { mreg[r] = -1e30f; lreg[r] = 0.f; }

    const int kTop = qb + 127;  // this pass's max causal k
    bf16x8 kreg = *(const bf16x8*)(kSrc + (size_t)s_row * 2304 + s_col);
    bf16x8 vreg = *(const bf16x8*)(vSrc + s_col);

    for (int k0 = 0; k0 <= kTop; k0 += 64) {
      __syncthreads();  // all waves done reading previous tile (covers cross-pass too)
      *(bf16x8*)(&lK[s_row * 80 + s_col]) = kreg;
      *(bf16x8*)(&lV[s_row * 80 + s_col]) = vreg;
      __syncthreads();  // tile visible
      if (k0 + 64 <= kTop) {  // prefetch next tile under compute
        kreg = *(const bf16x8*)(kSrc + (size_t)(k0 + 64 + s_row) * 2304 + s_col);
        vreg = *(const bf16x8*)(vSrc + k0 + 64 + s_col);
      }
      if (k0 <= qa + 15) {  // wave-uniform causal predicate
#pragma unroll
        for (int ks = 0; ks < 2; ++ks) {
          const int kg = k0 + ks * 32;
          f32x4 s0 = (f32x4){0.f, 0.f, 0.f, 0.f}, s1 = (f32x4){0.f, 0.f, 0.f, 0.f};
          {
            bf16x8 ka = *(const bf16x8*)(&lK[(ks * 32 + lr) * 80 + hi * 8]);
            bf16x8 kc = *(const bf16x8*)(&lK[(ks * 32 + lr) * 80 + hi * 8 + 32]);
            s0 = mfma_bf16(qf0, ka, s0);
            s0 = mfma_bf16(qf1, kc, s0);
            bf16x8 kd = *(const bf16x8*)(&lK[(ks * 32 + 16 + lr) * 80 + hi * 8]);
            bf16x8 ke = *(const bf16x8*)(&lK[(ks * 32 + 16 + lr) * 80 + hi * 8 + 32]);
            s1 = mfma_bf16(qf0, kd, s1);
            s1 = mfma_bf16(qf1, ke, s1);
          }
          float cor[4];
#pragma unroll
          for (int r = 0; r < 4; ++r) {
            int qrow = qa + hi * 4 + r;
            float v0 = s0[r] * SCL;
            if (kg + lr > qrow) v0 = -1e30f;
            float v1 = s1[r] * SCL;
            if (kg + 16 + lr > qrow) v1 = -1e30f;
            s0[r] = v0; s1[r] = v1;
            float m = fmaxf(v0, v1);
            m = fmaxf(m, __shfl_xor(m, 1));
            m = fmaxf(m, __shfl_xor(m, 2));
            m = fmaxf(m, __shfl_xor(m, 4));
            m = fmaxf(m, __shfl_xor(m, 8));
            float mnew = fmaxf(mreg[r], m);
            cor[r] = fexp2(mreg[r] - mnew);
            mreg[r] = mnew;
          }
#pragma unroll
          for (int r = 0; r < 4; ++r) {
            float p0 = fexp2(s0[r] - mreg[r]);
            float p1 = fexp2(s1[r] - mreg[r]);
            lreg[r] = lreg[r] * cor[r] + p0 + p1;  // per-lane partial
            P[(hi * 4 + r) * 40 + lr] = f2bf(p0);
            P[(hi * 4 + r) * 40 + 16 + lr] = f2bf(p1);
#pragma unroll
            for (int ct = 0; ct < 4; ++ct) o[ct][r] *= cor[r];
          }
          bf16x8 pa = *(const bf16x8*)(&P[lr * 40 + hi * 8]);
#pragma unroll
          for (int ct = 0; ct < 4; ++ct) {
            bf16x8 vf = *(const bf16x8*)(&lV[(ct * 16 + lr) * 80 + ks * 32 + hi * 8]);
            o[ct] = mfma_bf16(pa, vf, o[ct]);
          }
        }
      }
    }

    float lfin[4];
#pragma unroll
    for (int r = 0; r < 4; ++r) {
      float l = lreg[r];
      l += __shfl_xor(l, 1);
      l += __shfl_xor(l, 2);
      l += __shfl_xor(l, 4);
      l += __shfl_xor(l, 8);
      lfin[r] = 1.f / l;
    }
#pragma unroll
    for (int ct = 0; ct < 4; ++ct)
#pragma unroll
      for (int r = 0; r < 4; ++r) {
        float ov = o[ct][r] * lfin[r];
        size_t n = rowb + qa + hi * 4 + r;
        ctx[n * DIM + h * 64 + ct * 16 + lr] = f2bf(ov);
      }
  }
}

extern "C" void kernel_launch(void* const* d_in, const int* in_sizes, int n_in,
                              void* d_out, int out_size, void* d_ws, size_t ws_size,
                              hipStream_t stream) {
  (void)in_sizes; (void)n_in; (void)out_size; (void)ws_size;
  const int* idx = (const int*)d_in[0];
  const float* wte = (const float*)d_in[1];
  const float* wpe = (const float*)d_in[2];
  const float* ln1w = (const float*)d_in[3];
  const float* ln1b = (const float*)d_in[4];
  const float* qkvw = (const float*)d_in[5];
  const float* outw = (const float*)d_in[6];
  const float* ln2w = (const float*)d_in[7];
  const float* ln2b = (const float*)d_in[8];
  const float* fc1w = (const float*)d_in[9];
  const float* fc2w = (const float*)d_in[10];
  const float* lnfw = (const float*)d_in[11];
  const float* lnfb = (const float*)d_in[12];
  float* out = (float*)d_out;  // reference output dtype is float32

  // ws holds only buffers live during the final logits GEMM (proven footprint).
  char* ws = (char*)d_ws;
  size_t off = 0;
  auto carve = [&](size_t bytes) {
    char* p = ws + off;
    off += (bytes + 255) & ~(size_t)255;
    return p;
  };
  u16* hb = (u16*)carve((size_t)NTOK * DIM * 2);   // post-LN bf16 (live at final GEMM)
  u16* wteb = (u16*)carve((size_t)VOCAB * DIM * 2);  // wte bf16 (live at final GEMM)

  // Everything dead before the final GEMM lives in d_out (824 MB), which the
  // final GEMM fully overwrites. Deterministic: rebuilt every call.
  char* os = (char*)d_out;
  size_t ooff = 0;
  auto ocarve = [&](size_t bytes) {
    char* p = os + ooff;
    ooff += (bytes + 255) & ~(size_t)255;
    return p;
  };
  float* xb = (float*)ocarve((size_t)NTOK * DIM * 4);      // residual stream f32
  u16* qkvb = (u16*)ocarve((size_t)NTOK * 3 * DIM * 2);    // qkv bf16
  u16* ctxb = (u16*)ocarve((size_t)NTOK * DIM * 2);        // attn output bf16
  u16* mhb = (u16*)ocarve((size_t)NTOK * 4 * DIM * 2);     // mlp hidden bf16
  u16* vTb = (u16*)ocarve((size_t)2 * NH * 64 * SEQ * 2);  // V transposed
  u16* qkvwb = (u16*)ocarve((size_t)NL * 1769472 * 2);     // all-layer bf16 weights
  u16* outwb = (u16*)ocarve((size_t)NL * 589824 * 2);
  u16* fc1wb = (u16*)ocarve((size_t)NL * 2359296 * 2);
  u16* fc2wb = (u16*)ocarve((size_t)NL * 2359296 * 2);     // total ~245 MB < 824 MB

  // one-time (per call) weight conversion: 5 launches
  cvt_k<<<2048, 256, 0, stream>>>(qkvw, qkvwb, NL * 442368);
  cvt_k<<<2048, 256, 0, stream>>>(outw, outwb, NL * 147456);
  cvt_k<<<2048, 256, 0, stream>>>(fc1w, fc1wb, NL * 589824);
  cvt_k<<<2048, 256, 0, stream>>>(fc2w, fc2wb, NL * 589824);
  cvt_k<<<2048, 256, 0, stream>>>(wte, wteb, 9649344);

  embed_k<<<3072, 256, 0, stream>>>(idx, wte, wpe, xb);

  for (int l = 0; l < NL; ++l) {
    ln_k<<<1024, 256, 0, stream>>>(xb, ln1w + l * DIM, ln1b + l * DIM, hb);
    gemm256<0><<<dim3(16, 9), 512, 0, stream>>>(hb, qkvwb + (size_t)l * 1769472,
                                                2304, 768, qkvb, nullptr);
    vtrans_k<<<dim3(32, 24), 256, 0, stream>>>(qkvb, vTb);
    flash_k<<<dim3(8, 24), 512, 0, stream>>>(qkvb, vTb, ctxb);
    gemm128p<2><<<dim3(32, 6), 256, 0, stream>>>(ctxb, outwb + (size_t)l * 589824,
                                                 768, 768, nullptr, xb);
    ln_k<<<1024, 256, 0, stream>>>(xb, ln2w + l * DIM, ln2b + l * DIM, hb);
    gemm256<1><<<dim3(16, 12), 512, 0, stream>>>(hb, fc1wb + (size_t)l * 2359296,
                                                 3072, 768, mhb, nullptr);
    gemm128p<2><<<dim3(32, 6), 256, 0, stream>>>(mhb, fc2wb + (size_t)l * 2359296,
                                                 768, 3072, nullptr, xb);
  }

  ln_k<<<1024, 256, 0, stream>>>(xb, lnfw, lnfb, hb);
  gemm256<3><<<dim3(16, 197), 512, 0, stream>>>(hb, wteb, VOCAB, 768, nullptr, out);
}